// Round 1
// baseline (85.530 us; speedup 1.0000x reference)
//
#include <hip/hip_runtime.h>
#include <math.h>

// EDSCW 2x2/stride-2 pooling, f32 in/out.
// x: (B=16, C=96, H=224, W=224) -> out: (B,C,112,112)
// Per window {v0..v3}: m = mean; dsc = 2*v*m/(v^2+m^2); w = exp(dsc);
// out = sum(w*v)/sum(w); nan_to_num at the end.

#define IN_HW  (224 * 224)   // 50176
#define OUT_HW (112 * 112)   // 12544
#define OW     112
#define IW     224

__device__ __forceinline__ float edscw_window(float v0, float v1, float v2, float v3) {
    float m  = 0.25f * ((v0 + v1) + (v2 + v3));
    float m2 = m * m;
    float sw = 0.0f, swv = 0.0f;
    float vs[4] = {v0, v1, v2, v3};
#pragma unroll
    for (int k = 0; k < 4; ++k) {
        float v   = vs[k];
        // dsc in [-1,1]; 0/0 -> NaN (v==0 && m==0), matches reference propagation
        float dsc = __fdividef(2.0f * v * m, v * v + m2);
        float w   = __expf(dsc);
        sw  += w;
        swv += w * v;
    }
    float o = __fdividef(swv, sw);
    // jnp.nan_to_num defaults: NaN->0, +inf->FLT_MAX, -inf->-FLT_MAX
    if (isnan(o))      o = 0.0f;
    else if (isinf(o)) o = (o > 0.0f) ? 3.4028234663852886e38f : -3.4028234663852886e38f;
    return o;
}

__global__ __launch_bounds__(256) void edscw_pool2d_kernel(
        const float* __restrict__ in, float* __restrict__ out, int n_items) {
    // one work item = 2 adjacent output pixels (one float4 per input row)
    int idx    = blockIdx.x * blockDim.x + threadIdx.x;
    int stride = gridDim.x * blockDim.x;
    for (int i = idx; i < n_items; i += stride) {
        int xp = i % (OW / 2);          // output-pair index within a row (56)
        int r  = i / (OW / 2);
        int oy = r % 112;
        int bc = r / 112;

        const float* row0 = in + (size_t)bc * IN_HW + (size_t)(2 * oy) * IW + (size_t)xp * 4;
        float4 a = *reinterpret_cast<const float4*>(row0);        // input row 2*oy
        float4 b = *reinterpret_cast<const float4*>(row0 + IW);   // input row 2*oy+1

        float2 res;
        res.x = edscw_window(a.x, a.y, b.x, b.y);
        res.y = edscw_window(a.z, a.w, b.z, b.w);

        float* op = out + (size_t)bc * OUT_HW + (size_t)oy * OW + (size_t)xp * 2;
        *reinterpret_cast<float2*>(op) = res;
    }
}

extern "C" void kernel_launch(void* const* d_in, const int* in_sizes, int n_in,
                              void* d_out, int out_size, void* d_ws, size_t ws_size,
                              hipStream_t stream) {
    const float* x = (const float*)d_in[0];
    float* out     = (float*)d_out;
    const int n_items = out_size / 2;   // 2 output pixels per work item

    const int block = 256;
    const int grid  = 2048;             // grid-stride; ~8 blocks/CU on 256 CUs
    edscw_pool2d_kernel<<<grid, block, 0, stream>>>(x, out, n_items);
}

// Round 3
// 76.542 us; speedup vs baseline: 1.1174x; 1.1174x over previous
//
#include <hip/hip_runtime.h>
#include <math.h>

// EDSCW 2x2/stride-2 pooling, f32 in/out.
// x: (B=16, C=96, H=224, W=224) -> out: (B,C,112,112)
// Per window {v0..v3}: m = mean; dsc = 2*v*m/(v^2+m^2); w = exp(dsc);
// out = sum(w*v)/sum(w); nan_to_num at the end.

#define IN_HW  (224 * 224)   // 50176
#define OUT_HW (112 * 112)   // 12544
#define OW     112
#define IW     224

typedef float f32x4 __attribute__((ext_vector_type(4)));  // true vector type:
// __builtin_nontemporal_load/store requires it (HIP_vector_type struct is invalid)

__device__ __forceinline__ float edscw_window(float v0, float v1, float v2, float v3) {
    float m  = 0.25f * ((v0 + v1) + (v2 + v3));
    float m2 = m * m;
    float sw = 0.0f, swv = 0.0f;
    float vs[4] = {v0, v1, v2, v3};
#pragma unroll
    for (int k = 0; k < 4; ++k) {
        float v   = vs[k];
        // dsc in [-1,1]; 0/0 -> NaN (v==0 && m==0), matches reference propagation
        float dsc = __fdividef(2.0f * v * m, v * v + m2);
        float w   = __expf(dsc);
        sw  += w;
        swv += w * v;
    }
    float o = __fdividef(swv, sw);
    // jnp.nan_to_num defaults: NaN->0, +inf->FLT_MAX, -inf->-FLT_MAX
    if (isnan(o))      o = 0.0f;
    else if (isinf(o)) o = (o > 0.0f) ? 3.4028234663852886e38f : -3.4028234663852886e38f;
    return o;
}

__global__ __launch_bounds__(256) void edscw_pool2d_kernel(
        const float* __restrict__ in, float* __restrict__ out) {
    // one thread = 4 adjacent output pixels = 8 input cols x 2 rows (64B read, 16B store)
    int i  = blockIdx.x * 256 + threadIdx.x;    // exact fit: 18816*256 items
    int xq = i % (OW / 4);                      // quad index within output row (28)
    int r  = i / (OW / 4);
    int oy = r % 112;
    int bc = r / 112;

    const float* row0 = in + (size_t)bc * IN_HW + (size_t)(2 * oy) * IW + (size_t)xq * 8;
    const f32x4* p0 = reinterpret_cast<const f32x4*>(row0);
    const f32x4* p1 = reinterpret_cast<const f32x4*>(row0 + IW);

    f32x4 a0 = __builtin_nontemporal_load(p0);
    f32x4 a1 = __builtin_nontemporal_load(p0 + 1);
    f32x4 b0 = __builtin_nontemporal_load(p1);
    f32x4 b1 = __builtin_nontemporal_load(p1 + 1);

    f32x4 res;
    res.x = edscw_window(a0.x, a0.y, b0.x, b0.y);
    res.y = edscw_window(a0.z, a0.w, b0.z, b0.w);
    res.z = edscw_window(a1.x, a1.y, b1.x, b1.y);
    res.w = edscw_window(a1.z, a1.w, b1.z, b1.w);

    float* op = out + (size_t)bc * OUT_HW + (size_t)oy * OW + (size_t)xq * 4;
    __builtin_nontemporal_store(res, reinterpret_cast<f32x4*>(op));
}

extern "C" void kernel_launch(void* const* d_in, const int* in_sizes, int n_in,
                              void* d_out, int out_size, void* d_ws, size_t ws_size,
                              hipStream_t stream) {
    const float* x = (const float*)d_in[0];
    float* out     = (float*)d_out;

    // out_size = 19,267,584 pixels; 4 per thread -> 4,816,896 threads = 18816 * 256
    const int block = 256;
    const int grid  = (out_size / 4 + block - 1) / block;   // 18816, exact
    edscw_pool2d_kernel<<<grid, block, 0, stream>>>(x, out);
}

// Round 4
// 74.787 us; speedup vs baseline: 1.1437x; 1.0235x over previous
//
#include <hip/hip_runtime.h>
#include <math.h>

// EDSCW 2x2/stride-2 pooling, f32 in/out.
// x: (B=16, C=96, H=224, W=224) -> out: (B,C,112,112)
// Per window {v0..v3}: m = mean; dsc = 2*v*m/(v^2+m^2); w = exp(dsc);
// out = sum(w*v)/sum(w); nan_to_num at the end.
//
// Layout: one thread = 2 output cols x 2 output rows (4 px). Loads one float4
// from each of 4 consecutive input rows -> every load instruction is
// lane-contiguous (stride 16B across lanes), unlike the previous 8-col layout
// whose paired dwordx4s were stride-32B per instruction (half-line coverage).

#define IN_HW  (224 * 224)   // 50176
#define OUT_HW (112 * 112)   // 12544
#define OW     112
#define IW     224

typedef float f32x4 __attribute__((ext_vector_type(4)));
typedef float f32x2 __attribute__((ext_vector_type(2)));

__device__ __forceinline__ float edscw_window(float v0, float v1, float v2, float v3) {
    float m  = 0.25f * ((v0 + v1) + (v2 + v3));
    float m2 = m * m;
    float sw = 0.0f, swv = 0.0f;
    float vs[4] = {v0, v1, v2, v3};
#pragma unroll
    for (int k = 0; k < 4; ++k) {
        float v   = vs[k];
        // dsc in [-1,1]; 0/0 -> NaN (v==0 && m==0), matches reference propagation
        float dsc = __fdividef(2.0f * v * m, v * v + m2);
        float w   = __expf(dsc);
        sw  += w;
        swv += w * v;
    }
    float o = __fdividef(swv, sw);
    // jnp.nan_to_num defaults: NaN->0, +inf->FLT_MAX, -inf->-FLT_MAX
    if (isnan(o))      o = 0.0f;
    else if (isinf(o)) o = (o > 0.0f) ? 3.4028234663852886e38f : -3.4028234663852886e38f;
    return o;
}

__global__ __launch_bounds__(256) void edscw_pool2d_kernel(
        const float* __restrict__ in, float* __restrict__ out) {
    int i   = blockIdx.x * 256 + threadIdx.x;   // exact fit: 18816*256 threads
    int xp  = i % (OW / 2);                     // output col-pair   [0,56)
    int r   = i / (OW / 2);
    int oy2 = r % (112 / 2);                    // output row-pair   [0,56)
    int bc  = r / (112 / 2);

    const float* base = in + (size_t)bc * IN_HW + (size_t)(4 * oy2) * IW + (size_t)xp * 4;
    f32x4 r0 = __builtin_nontemporal_load(reinterpret_cast<const f32x4*>(base));
    f32x4 r1 = __builtin_nontemporal_load(reinterpret_cast<const f32x4*>(base + IW));
    f32x4 r2 = __builtin_nontemporal_load(reinterpret_cast<const f32x4*>(base + 2 * IW));
    f32x4 r3 = __builtin_nontemporal_load(reinterpret_cast<const f32x4*>(base + 3 * IW));

    f32x2 resA, resB;
    resA.x = edscw_window(r0.x, r0.y, r1.x, r1.y);   // out row 2*oy2
    resA.y = edscw_window(r0.z, r0.w, r1.z, r1.w);
    resB.x = edscw_window(r2.x, r2.y, r3.x, r3.y);   // out row 2*oy2+1
    resB.y = edscw_window(r2.z, r2.w, r3.z, r3.w);

    float* op = out + (size_t)bc * OUT_HW + (size_t)(2 * oy2) * OW + (size_t)xp * 2;
    __builtin_nontemporal_store(resA, reinterpret_cast<f32x2*>(op));
    __builtin_nontemporal_store(resB, reinterpret_cast<f32x2*>(op + OW));
}

extern "C" void kernel_launch(void* const* d_in, const int* in_sizes, int n_in,
                              void* d_out, int out_size, void* d_ws, size_t ws_size,
                              hipStream_t stream) {
    const float* x = (const float*)d_in[0];
    float* out     = (float*)d_out;

    // out_size = 19,267,584 pixels; 4 per thread -> 4,816,896 threads = 18816 * 256
    const int block = 256;
    const int grid  = (out_size / 4 + block - 1) / block;   // 18816, exact
    edscw_pool2d_kernel<<<grid, block, 0, stream>>>(x, out);
}